// Round 2
// baseline (68.223 us; speedup 1.0000x reference)
//
#include <hip/hip_runtime.h>
#include <math.h>

// HiPPO-LegS reconstruction: out = sum_{i=1..256} coef[i-1]*sqrt(2i+1)*P_i(x),
// x = 2t/curr_t - 1.
//
// R1 post-mortem: full 255-step unroll -> ~40KB straight-line code > 32KB I$,
// instruction-fetch bound (67us = ~18 cyc/instr). Fix: compact loop + LDS table.
//
// Rescaled recurrence (3 VALU/step instead of 4):
//   S_d = P_d / g_d,  g_{d+1} = g_d*(2d+1)/(2d+2), g_0=2, g_1=1
//   => S_{d+1} = (2x)*S_d - beta_d*S_{d-1},  beta_d = 4d^2/(4d^2-1)
//   out = sum_i w'_i * S_i,  w'_i = coef[i-1]*sqrt(2i+1)*g_i
//   g_i = 2*C(2i,i)/4^i  in [0.07, 1] -- fp32-safe for all i<=256.

#define NPAIR 128  // 128 fused step-pairs cover d=1..256 (d=256 weight = 0)

__device__ inline float g_of(float fi) {
    // ln g_i = lgamma(2i) - (i-1)*ln4 - lgamma(i) - lgamma(i+1)
    float lg = lgammaf(2.0f * fi) - (fi - 1.0f) * 1.3862943611f
             - lgammaf(fi) - lgammaf(fi + 1.0f);
    return expf(lg);
}

__device__ inline float wp_of(int i, const float* __restrict__ coef) {
    if (i > 256) return 0.0f;  // padding step d=256 contributes nothing
    float fi = (float)i;
    return coef[i - 1] * sqrtf(2.0f * fi + 1.0f) * g_of(fi);
}

__global__ __launch_bounds__(256) void hippo_kernel(
    const float* __restrict__ t,
    const float* __restrict__ coef,
    const int* __restrict__ curr_t,
    float* __restrict__ out,
    int n4)
{
    // tab[m] = {beta(2m+1), w'(2m+2), beta(2m+2), w'(2m+3)}; entry NPAIR is a
    // zero pad so the software prefetch can read one past the end.
    __shared__ float4 tab[NPAIR + 1];
    const int tid = threadIdx.x;

    if (tid <= NPAIR) {
        if (tid < NPAIR) {
            const float d1 = 2.0f * (float)tid + 1.0f;
            const float d2 = d1 + 1.0f;
            const float b1 = 4.0f * d1 * d1 / (4.0f * d1 * d1 - 1.0f);
            const float b2 = 4.0f * d2 * d2 / (4.0f * d2 * d2 - 1.0f);
            const float w1 = wp_of(2 * tid + 2, coef);
            const float w2 = wp_of(2 * tid + 3, coef);
            tab[tid] = make_float4(b1, w1, b2, w2);
        } else {
            tab[NPAIR] = make_float4(0.0f, 0.0f, 0.0f, 0.0f);
        }
    }
    __syncthreads();

    const int gid = blockIdx.x * 256 + tid;
    if (gid >= n4) return;

    const float s = 2.0f / (float)curr_t[0];

    // 4 elements/thread: one float4 load, 4 independent chains (ILP).
    float4 tv = reinterpret_cast<const float4*>(t)[gid];
    float x[4] = { tv.x * s - 1.0f, tv.y * s - 1.0f,
                   tv.z * s - 1.0f, tv.w * s - 1.0f };

    const float wp1 = coef[0] * 1.7320508075688772f;  // w'_1 = coef[0]*sqrt(3)*g_1
    float X[4], S[4], Sm1[4], acc[4];
#pragma unroll
    for (int e = 0; e < 4; ++e) {
        X[e]   = 2.0f * x[e];
        S[e]   = x[e];        // S_1 = P_1/g_1 = x
        Sm1[e] = 0.5f;        // S_0 = P_0/g_0 = 1/2
        acc[e] = wp1 * x[e];  // degree-1 term
    }

    float4 c = tab[0];
#pragma unroll 2
    for (int m = 0; m < NPAIR; ++m) {
        float4 cn = tab[m + 1];  // broadcast ds_read_b128, prefetched
#pragma unroll
        for (int e = 0; e < 4; ++e) {
            // step 2m+1: S_{d+1} = X*S - beta*Sm1
            float t1  = c.x * Sm1[e];
            float sn1 = fmaf(X[e], S[e], -t1);
            acc[e] = fmaf(c.y, sn1, acc[e]);
            // step 2m+2 (old S becomes S_{d-1})
            float t2  = c.z * S[e];
            float sn2 = fmaf(X[e], sn1, -t2);
            acc[e] = fmaf(c.w, sn2, acc[e]);
            Sm1[e] = sn1;
            S[e]   = sn2;
        }
        c = cn;
    }

    reinterpret_cast<float4*>(out)[gid] =
        make_float4(acc[0], acc[1], acc[2], acc[3]);
}

extern "C" void kernel_launch(void* const* d_in, const int* in_sizes, int n_in,
                              void* d_out, int out_size, void* d_ws, size_t ws_size,
                              hipStream_t stream)
{
    const float* t      = (const float*)d_in[0];
    const float* coef   = (const float*)d_in[1];
    const int*   curr_t = (const int*)d_in[2];
    float*       out    = (float*)d_out;

    int n  = in_sizes[0];   // 524288 = 4 * 131072
    int n4 = n >> 2;
    int blocks = (n4 + 255) / 256;  // 512 blocks -> 2 blocks/CU
    hippo_kernel<<<blocks, 256, 0, stream>>>(t, coef, curr_t, out, n4);
}